// Round 7
// baseline (169.259 us; speedup 1.0000x reference)
//
#include <hip/hip_runtime.h>

// ---------------------------------------------------------------------------
// MultiScaleResidualVectorQuantize: 4-stage residual VQ, strides (8,4,2,1)
// e_i = P_i - sum_{j<i} tab_ij[idx_j]  with P_i = iw_i*pool_i(z)+ib_i and
// tab_ij[code] = M_ij*cb_j[code] + v_ij  (f64 precompute, f32 table).
// One read of z, one write of z_q; cascade entirely in C=8 space.
// 6 launches: [pool+prep] -> [vq0+tabgen] -> vq1 -> vq2 -> vq3 -> zq.
// ---------------------------------------------------------------------------

constexpr int B = 16, D = 512, T = 4096, C = 8, K = 1024, NS = 4;

// output offsets (floats, concatenated in reference return order)
constexpr long long OUT_ZQ     = 0;                       // 16*512*4096
constexpr long long OUT_LAT    = 33554432LL;              // 16*32*4096
constexpr long long OUT_COMMIT = OUT_LAT + 2097152LL;     // 35651584
constexpr long long OUT_CBL    = OUT_COMMIT + 1;          // 35651585
constexpr long long OUT_CODES0 = OUT_CBL + 1;             // 35651586

__host__ __device__ constexpr long long code_off(int j) {
    return OUT_CODES0 + (j >= 1 ? 8192 : 0) + (j >= 2 ? 16384 : 0) + (j >= 3 ? 32768 : 0);
}

// workspace offsets (floats)
constexpr long long WS_CBREC = 0;                 // 4*1024*12
constexpr long long WS_OBS   = 49152;             // 512 (sum of out biases)
constexpr long long WS_LOSS  = 49664;             // 1
constexpr long long WS_CORR  = 49696;             // doubles: 6 pairs * 72
constexpr long long WS_P0    = 52224;             // 8192*8
constexpr long long WS_P1    = WS_P0 + 65536;
constexpr long long WS_P2    = WS_P1 + 131072;
constexpr long long WS_P3    = WS_P2 + 262144;
constexpr long long WS_Q0    = WS_P3 + 524288;
constexpr long long WS_Q1    = WS_Q0 + 65536;
constexpr long long WS_Q2    = WS_Q1 + 131072;
constexpr long long WS_Q3    = WS_Q2 + 262144;
constexpr long long WS_TAB   = WS_Q3 + 524288;    // 6*1024*8 f32; ends ~8.27MB

// ---------------------------------------------------------------------------
// k_pool_prep: blocks 0..511 = pooled projections (one pass over z);
// blocks 512..520 = codebook records + summed bias + loss=0;
// blocks 521..574 = correction terms M_ij/v_ij in f64 (one wave per scalar).
// (prep parts are independent of pool; pool does not read their outputs.)
// ---------------------------------------------------------------------------
__global__ __launch_bounds__(512) void k_pool_prep(
    const float* __restrict__ z, const float* __restrict__ in_w,
    const float* __restrict__ in_b, const float* __restrict__ out_w,
    const float* __restrict__ out_b, const float* __restrict__ cb,
    float* __restrict__ ws)
{
    __shared__ float smem[512 * 36];     // 72 KB: in_w [d][36], later reduction tree

    int bid = blockIdx.x;
    int tid = threadIdx.x;
    int lane = tid & 63;

    if (bid >= 512) {
        if (bid < 521) {
            // --- codebook records + obs + loss zero ---
            int t = (bid - 512) * 512 + tid;
            if (t == 0) ws[WS_LOSS] = 0.f;
            if (t < NS * K) {
                const float* c = cb + (long long)t * 8;
                float cv[8];
#pragma unroll
                for (int k = 0; k < 8; k++) cv[k] = c[k];
                float n2 = 0.f;
#pragma unroll
                for (int k = 0; k < 8; k++) n2 += cv[k] * cv[k];
                float den = fmaxf(sqrtf(n2), 1e-12f);
                float cn[8];
#pragma unroll
                for (int k = 0; k < 8; k++) cn[k] = cv[k] / den;
                float cn2 = 0.f;
#pragma unroll
                for (int k = 0; k < 8; k++) cn2 += cn[k] * cn[k];
                float* r = ws + WS_CBREC + (long long)t * 12;
#pragma unroll
                for (int k = 0; k < 8; k++) r[k] = -2.0f * cn[k];
                r[8] = cn2; r[9] = 0.f; r[10] = 0.f; r[11] = 0.f;
            } else if (t < NS * K + D) {
                int d = t - NS * K;
                ws[WS_OBS + d] = out_b[d] + out_b[512 + d] + out_b[1024 + d] + out_b[1536 + d];
            }
        } else {
            // --- correction terms (f64) ---
            int gw = (bid - 521) * 8 + (tid >> 6);
            if (gw >= 6 * 72) return;
            int p = gw / 72, idx = gw % 72;
            int i, j;
            if (p == 0) { i = 1; j = 0; }
            else if (p < 3) { i = 2; j = p - 1; }
            else { i = 3; j = p - 3; }

            double acc = 0.0;
            if (idx < 64) {
                int ci = idx >> 3, cc = idx & 7;
                const float* wi = in_w + (long long)(i * 8 + ci) * 512;
                const float* wo = out_w + (long long)j * 4096;      // [d][8]
#pragma unroll
                for (int k = 0; k < 8; k++) {
                    int d = lane + k * 64;
                    acc += (double)wi[d] * (double)wo[d * 8 + cc];
                }
            } else {
                int ci = idx - 64;
                const float* wi = in_w + (long long)(i * 8 + ci) * 512;
                const float* bo = out_b + (long long)j * 512;
#pragma unroll
                for (int k = 0; k < 8; k++) {
                    int d = lane + k * 64;
                    acc += (double)wi[d] * (double)bo[d];
                }
            }
#pragma unroll
            for (int off = 32; off >= 1; off >>= 1) acc += __shfl_down(acc, off);
            if (lane == 0) ((double*)(ws + WS_CORR))[p * 72 + idx] = acc;
        }
        return;
    }

    // --- pool + projection part ---
    int wv = __builtin_amdgcn_readfirstlane(tid >> 6);   // dseg, wave-uniform
    int b = bid & 15;
    int t0 = (bid >> 4) * 128;

    // stage in_w -> LDS transposed
#pragma unroll
    for (int sc = 0; sc < 32; ++sc)
        smem[tid * 36 + sc] = in_w[sc * 512 + tid];
    __syncthreads();

    const float* zrow = z + ((long long)b * D) * T + t0 + lane * 2;

    float a3[2][8] = {};
    float a2[8]    = {};
    float a1[8]    = {};
    float a0[8]    = {};

    // 2-deep z prefetch pipeline
    float2 zv0 = *(const float2*)(zrow + (long long)(wv * 64 + 0) * T);
    float2 zv1 = *(const float2*)(zrow + (long long)(wv * 64 + 1) * T);

#pragma unroll 2
    for (int dd = 0; dd < 64; dd++) {
        int d = wv * 64 + dd;
        float2 v = zv0;
        zv0 = zv1;
        if (dd < 62)
            zv1 = *(const float2*)(zrow + (long long)(d + 2) * T);

        const float* wrow = smem + d * 36;
        float w0[8], w1[8], w2[8], w3[8];
        *(float4*)&w0[0] = *(const float4*)(wrow + 0);
        *(float4*)&w0[4] = *(const float4*)(wrow + 4);
        *(float4*)&w1[0] = *(const float4*)(wrow + 8);
        *(float4*)&w1[4] = *(const float4*)(wrow + 12);
        *(float4*)&w2[0] = *(const float4*)(wrow + 16);
        *(float4*)&w2[4] = *(const float4*)(wrow + 20);
        *(float4*)&w3[0] = *(const float4*)(wrow + 24);
        *(float4*)&w3[4] = *(const float4*)(wrow + 28);

        float s2 = v.x + v.y;
#pragma unroll
        for (int c = 0; c < 8; c++) {
            a3[0][c] = fmaf(w3[c], v.x, a3[0][c]);
            a3[1][c] = fmaf(w3[c], v.y, a3[1][c]);
            a2[c]    = fmaf(w2[c], s2, a2[c]);
            a1[c]    = fmaf(w1[c], s2, a1[c]);
            a0[c]    = fmaf(w0[c], s2, a0[c]);
        }
    }

    __syncthreads();

    {
        float (*red)[16][64] = (float (*)[16][64])smem;
#pragma unroll
        for (int pos = 0; pos < 2; pos++)
#pragma unroll
            for (int c = 0; c < 8; c++)
                red[wv][pos * 8 + c][lane] = a3[pos][c];
        __syncthreads();
        for (int o = tid; o < 1024; o += 512) {
            int ln = o & 63, s = o >> 6;
            float sum = 0.f;
#pragma unroll
            for (int w = 0; w < 8; w++) sum += red[w][s][ln];
            int pos = s >> 3, c = s & 7;
            int tp = t0 + ln * 2 + pos;
            ws[WS_P3 + ((long long)b * 4096 + tp) * 8 + c] = sum + in_b[3 * 8 + c];
        }
        __syncthreads();
    }

    {
        float (*red)[24][64] = (float (*)[24][64])smem;
#pragma unroll
        for (int c = 0; c < 8; c++) {
            red[wv][c][lane]      = a2[c];
            red[wv][8 + c][lane]  = a1[c];
            red[wv][16 + c][lane] = a0[c];
        }
        __syncthreads();
        for (int o = tid; o < 1536; o += 512) {
            int ln = o & 63, s = o >> 6;
            if (s < 8) {
                int c = s;
                float sum = 0.f;
#pragma unroll
                for (int w = 0; w < 8; w++) sum += red[w][s][ln];
                int tp = (t0 >> 1) + ln;
                ws[WS_P2 + ((long long)b * 2048 + tp) * 8 + c] = sum * 0.5f + in_b[2 * 8 + c];
            } else if (s < 16) {
                if (ln >= 32) continue;
                int c = s - 8;
                float sum = 0.f;
#pragma unroll
                for (int w = 0; w < 8; w++) sum += red[w][s][2 * ln] + red[w][s][2 * ln + 1];
                int tp = (t0 >> 2) + ln;
                ws[WS_P1 + ((long long)b * 1024 + tp) * 8 + c] = sum * 0.25f + in_b[8 + c];
            } else {
                if (ln >= 16) continue;
                int c = s - 16;
                float sum = 0.f;
#pragma unroll
                for (int w = 0; w < 8; w++)
#pragma unroll
                    for (int k = 0; k < 4; k++) sum += red[w][s][4 * ln + k];
                int tp = (t0 >> 3) + ln;
                ws[WS_P0 + ((long long)b * 512 + tp) * 8 + c] = sum * 0.125f + in_b[c];
            }
        }
    }
}

// ---------------------------------------------------------------------------
// k_vq<S>: block = 128 vectors x 8 waves (512 thr); each lane owns 2 vectors
// (shared record reads -> half the DS traffic, 2 FMA chains for ILP).
// Records in LDS; sb/si argmin buffers aliased into the record buffer after
// the scan (extra barrier) -> 52KB LDS, 3 blocks/CU. e from P minus table
// gathers (f64 accumulate; indices from earlier-stage codes in out).
// S==0 additionally generates the gather tables (consumed from vq1 on).
// ---------------------------------------------------------------------------
template <int S>
__global__ __launch_bounds__(512) void k_vq(
    const float* __restrict__ cb, float* __restrict__ ws, float* __restrict__ out)
{
    constexpr int TS = 512 << S;
    constexpr long long PBASE = (S == 0) ? WS_P0 : (S == 1) ? WS_P1 : (S == 2) ? WS_P2 : WS_P3;
    constexpr long long QBASE = (S == 0) ? WS_Q0 : (S == 1) ? WS_Q1 : (S == 2) ? WS_Q2 : WS_Q3;
    constexpr int pbase = (S == 1) ? 0 : (S == 2) ? 1 : 3;
    constexpr float LW = 1.0f / (8.0f * (float)TS * (float)B);

    __shared__ float cbl[12288];            // 48 KB records; aliased sb/si after scan
    __shared__ float e_lds[128][8];         // 4 KB

    int tid = threadIdx.x;
    int lane = tid & 63;
    int w = __builtin_amdgcn_readfirstlane(tid >> 6);
    int bid = blockIdx.x;

    // stage records -> LDS (float4, coalesced)
    {
        const float4* src = (const float4*)(ws + WS_CBREC + (long long)S * K * 12);
        float4* dst = (float4*)cbl;
        for (int o = tid; o < 3072; o += 512) dst[o] = src[o];
    }

    // e for this lane's two vectors (v, v+64)
    float enA[8], enB[8];
    {
        long long vv[2] = { (long long)bid * 128 + lane, (long long)bid * 128 + 64 + lane };
#pragma unroll
        for (int h = 0; h < 2; h++) {
            long long v = vv[h];
            int b = (int)(v >> (9 + S));
            int tp = (int)(v & (TS - 1));
            float e[8];
            const float* P = ws + PBASE + v * 8;
#pragma unroll
            for (int c = 0; c < 8; c++) e[c] = P[c];
            if (S > 0) {
                double ed[8];
#pragma unroll
                for (int c = 0; c < 8; c++) ed[c] = (double)e[c];
#pragma unroll
                for (int j = 0; j < S; j++) {
                    int tj = tp >> (S - j);
                    long long vj = ((long long)b << (9 + j)) + tj;
                    int cidx = (int)out[code_off(j) + vj];
                    const float* trow = ws + WS_TAB + ((long long)(pbase + j) * 1024 + cidx) * 8;
#pragma unroll
                    for (int c = 0; c < 8; c++) ed[c] -= (double)trow[c];
                }
#pragma unroll
                for (int c = 0; c < 8; c++) e[c] = (float)ed[c];
            }
            float n2 = 0.f;
#pragma unroll
            for (int c = 0; c < 8; c++) n2 = fmaf(e[c], e[c], n2);
            float den = fmaxf(sqrtf(n2), 1e-12f);
            float inv = 1.0f / den;
            float* en = h ? enB : enA;
#pragma unroll
            for (int c = 0; c < 8; c++) en[c] = e[c] * inv;
            if (w == 0) {
#pragma unroll
                for (int c = 0; c < 8; c++) e_lds[h * 64 + lane][c] = e[c];
            }
        }
    }

    __syncthreads();   // cbl staged + e_lds ready

    // scan this wave's 128-code chunk for both vectors
    const float* rec = cbl + w * 128 * 12;
    float bestA = 3.0e38f, bestB = 3.0e38f;
    int idxA = 0, idxB = 0;
#pragma unroll 2
    for (int jt = 0; jt < 128; jt++) {
        const float* r = rec + jt * 12;
        float aA = r[8], aB = r[8];                  // cn2
#pragma unroll
        for (int c = 0; c < 8; c++) {
            float rc = r[c];
            aA = fmaf(rc, enA[c], aA);               // - 2*dot
            aB = fmaf(rc, enB[c], aB);
        }
        if (aA < bestA) { bestA = aA; idxA = jt; }
        if (aB < bestB) { bestB = aB; idxB = jt; }
    }

    __syncthreads();   // all waves done reading cbl -> safe to alias

    float* sb_f = cbl;                               // [8][128]
    unsigned short* si_u = (unsigned short*)(cbl + 1024);  // [8][128]
    sb_f[w * 128 + lane]      = bestA;
    sb_f[w * 128 + 64 + lane] = bestB;
    si_u[w * 128 + lane]      = (unsigned short)(w * 128 + idxA);
    si_u[w * 128 + 64 + lane] = (unsigned short)(w * 128 + idxB);
    __syncthreads();

    if (tid < 128) {
        int sv = tid;
        float bd = sb_f[sv];
        int bj = si_u[sv];
#pragma unroll
        for (int ww = 1; ww < 8; ww++) {
            float d2 = sb_f[ww * 128 + sv];
            int j2 = si_u[ww * 128 + sv];
            if (d2 < bd || (d2 == bd && j2 < bj)) { bd = d2; bj = j2; }
        }
        long long v = (long long)bid * 128 + sv;
        // unnormalized codebook lookup
        const float* qc = cb + ((long long)S * K + bj) * 8;
        float qv[8];
#pragma unroll
        for (int c = 0; c < 8; c++) qv[c] = qc[c];
        float* qo = ws + QBASE + v * 8;
#pragma unroll
        for (int c = 0; c < 8; c++) qo[c] = qv[c];

        out[code_off(S) + v] = (float)bj;

        // commit/cb loss (identical values)
        float l = 0.f;
#pragma unroll
        for (int c = 0; c < 8; c++) { float dq = e_lds[sv][c] - qv[c]; l = fmaf(dq, dq, l); }
#pragma unroll
        for (int off = 32; off >= 1; off >>= 1) l += __shfl_down(l, off);
        if ((tid & 63) == 0) atomicAdd(ws + WS_LOSS, l * LW);
    }

    // cooperative latents write, float4 (1024*SREP floats per block)
    constexpr int SREP = 8 >> S;
    constexpr int SH = 3 - S;
    {
        long long v0 = (long long)bid * 128;
        int b0 = (int)(v0 >> (9 + S));
        int tp0 = (int)(v0 & (TS - 1));
        long long lat0 = OUT_LAT + ((long long)b0 * 32 + S * 8) * T + (long long)tp0 * SREP;
        for (int o = tid; o < 256 * SREP; o += 512) {
            int c = o / (32 * SREP);
            int i4 = o % (32 * SREP);
            int r0 = i4 * 4;
            float4 vv = make_float4(
                e_lds[(r0 + 0) >> SH][c], e_lds[(r0 + 1) >> SH][c],
                e_lds[(r0 + 2) >> SH][c], e_lds[(r0 + 3) >> SH][c]);
            *(float4*)(out + lat0 + (long long)c * T + r0) = vv;
        }
    }

    // S==0 tail: generate gather tables (needed by vq1.. only)
    if constexpr (S == 0) {
        if (bid < 12) {
            int t = bid * 512 + tid;
            if (t < 6 * 1024) {
                int p = t >> 10, code = t & 1023;
                int j = (p == 0) ? 0 : (p < 3) ? (p - 1) : (p - 3);
                const double* M = (const double*)(ws + WS_CORR) + p * 72;
                const float* q = cb + ((long long)j * K + code) * 8;
                float qvv[8];
#pragma unroll
                for (int cc = 0; cc < 8; cc++) qvv[cc] = q[cc];
                float* trow = ws + WS_TAB + (long long)t * 8;
#pragma unroll
                for (int c = 0; c < 8; c++) {
                    double acc = M[64 + c];
#pragma unroll
                    for (int cc = 0; cc < 8; cc++) acc += M[c * 8 + cc] * (double)qvv[cc];
                    trow[c] = (float)acc;
                }
            }
        }
    }
}

// ---------------------------------------------------------------------------
// k_zq (unchanged): lane owns 4 t -> float4 stores; 4096 blocks.
// ---------------------------------------------------------------------------
__global__ __launch_bounds__(256) void k_zq(
    const float* __restrict__ out_w, const float* __restrict__ ws, float* __restrict__ out)
{
    int tid = threadIdx.x;
    int lane = tid & 63;
    int w = __builtin_amdgcn_readfirstlane(tid >> 6);
    int bid = blockIdx.x;                 // 4096 = 16 b * 64 dgrp * 4 tchunk
    int tc   = bid & 3;
    int g    = (bid >> 2) & 63;
    int b    = bid >> 8;
    int t    = tc * 1024 + w * 256 + lane * 4;

    float q0[8], q1[8], q2[2][8], q3[4][8];
    {
        const float* Q = ws + WS_Q0 + ((long long)b * 512 + (t >> 3)) * 8;
#pragma unroll
        for (int c = 0; c < 8; c++) q0[c] = Q[c];
    }
    {
        const float* Q = ws + WS_Q1 + ((long long)b * 1024 + (t >> 2)) * 8;
#pragma unroll
        for (int c = 0; c < 8; c++) q1[c] = Q[c];
    }
    {
        const float* Q = ws + WS_Q2 + ((long long)b * 2048 + (t >> 1)) * 8;
#pragma unroll
        for (int j = 0; j < 2; j++)
#pragma unroll
            for (int c = 0; c < 8; c++) q2[j][c] = Q[j * 8 + c];
    }
    {
        const float* Q = ws + WS_Q3 + ((long long)b * 4096 + t) * 8;
#pragma unroll
        for (int j = 0; j < 4; j++)
#pragma unroll
            for (int c = 0; c < 8; c++) q3[j][c] = Q[j * 8 + c];
    }

#pragma unroll 2
    for (int dl = 0; dl < 8; dl++) {
        int d = g * 8 + dl;
        const float* w0 = out_w + 0 * 4096 + d * 8;
        const float* w1 = out_w + 1 * 4096 + d * 8;
        const float* w2 = out_w + 2 * 4096 + d * 8;
        const float* w3 = out_w + 3 * 4096 + d * 8;

        float acc = ws[WS_OBS + d];
#pragma unroll
        for (int c = 0; c < 8; c++) acc = fmaf(w0[c], q0[c], acc);
#pragma unroll
        for (int c = 0; c < 8; c++) acc = fmaf(w1[c], q1[c], acc);
        float accA = acc, accB = acc;
#pragma unroll
        for (int c = 0; c < 8; c++) {
            accA = fmaf(w2[c], q2[0][c], accA);
            accB = fmaf(w2[c], q2[1][c], accB);
        }
        float r0 = accA, r1 = accA, r2 = accB, r3 = accB;
#pragma unroll
        for (int c = 0; c < 8; c++) {
            r0 = fmaf(w3[c], q3[0][c], r0);
            r1 = fmaf(w3[c], q3[1][c], r1);
            r2 = fmaf(w3[c], q3[2][c], r2);
            r3 = fmaf(w3[c], q3[3][c], r3);
        }
        float* o = out + OUT_ZQ + ((long long)b * 512 + d) * T + t;
        *(float4*)o = make_float4(r0, r1, r2, r3);
    }

    if (bid == 0 && tid == 0) {
        float L = ws[WS_LOSS];
        out[OUT_COMMIT] = L;
        out[OUT_CBL]    = L;
    }
}

// ---------------------------------------------------------------------------
extern "C" void kernel_launch(void* const* d_in, const int* in_sizes, int n_in,
                              void* d_out, int out_size, void* d_ws, size_t ws_size,
                              hipStream_t stream)
{
    const float* z     = (const float*)d_in[0];
    const float* in_w  = (const float*)d_in[1];
    const float* in_b  = (const float*)d_in[2];
    const float* out_w = (const float*)d_in[3];
    const float* out_b = (const float*)d_in[4];
    const float* cb    = (const float*)d_in[5];
    float* out = (float*)d_out;
    float* ws  = (float*)d_ws;

    k_pool_prep<<<dim3(575), dim3(512), 0, stream>>>(z, in_w, in_b, out_w, out_b, cb, ws);
    k_vq<0><<<dim3(64),  dim3(512), 0, stream>>>(cb, ws, out);
    k_vq<1><<<dim3(128), dim3(512), 0, stream>>>(cb, ws, out);
    k_vq<2><<<dim3(256), dim3(512), 0, stream>>>(cb, ws, out);
    k_vq<3><<<dim3(512), dim3(512), 0, stream>>>(cb, ws, out);
    k_zq<<<dim3(4096), dim3(256), 0, stream>>>(out_w, ws, out);
}